// Round 6
// baseline (355.277 us; speedup 1.0000x reference)
//
#include <hip/hip_runtime.h>
#include <hip/hip_bf16.h>
#include <math.h>

#define NB 32
#define NT 2048
#define NC 1024
#define NM 131072
#define TOPK 8
#define TCH 32              // t-chunks for mean
#define MBLK 128            // m rows per score block
#define SBLOCKS (NM / MBLK) // 1024
#define TROW 129            // padded tile row (float4 units)

// ws layout (float offsets). candS/candI OVERLAY part (part is dead after
// mean_finalize_k; scores_topk_k runs after qproj_k on the same stream).
#define OFF_PART 0
#define OFF_CS   0
#define OFF_CI   262144
#define OFF_MEAN 1048576
#define OFF_Q    (OFF_MEAN + 32768)

__global__ __launch_bounds__(256) void mean_partial_k(const float* __restrict__ seg,
                                                      float* __restrict__ part) {
    int blk = blockIdx.x;            // 1024 = 32 b * 32 tc
    int b = blk >> 5, tc = blk & 31;
    int tid = threadIdx.x;
    const float4* src = (const float4*)(seg + ((size_t)b * NT + (size_t)tc * 64) * NC);
    float4 acc = make_float4(0.f, 0.f, 0.f, 0.f);
#pragma unroll 4
    for (int t = 0; t < 64; ++t) {
        float4 v = src[(size_t)t * 256 + tid];
        acc.x += v.x; acc.y += v.y; acc.z += v.z; acc.w += v.w;
    }
    ((float4*)(part + ((size_t)b * 32 + tc) * NC))[tid] = acc;
}

__global__ __launch_bounds__(256) void mean_finalize_k(const float* __restrict__ part,
                                                       float* __restrict__ mean) {
    int i = blockIdx.x * 256 + threadIdx.x;   // 32768
    int b = i >> 10, c = i & 1023;
    float s = 0.f;
#pragma unroll
    for (int tc = 0; tc < 32; ++tc) s += part[((size_t)b * 32 + tc) * NC + c];
    mean[i] = s * (1.0f / NT);
}

__global__ __launch_bounds__(256) void qproj_k(const float* __restrict__ mean,
                                               const float* __restrict__ Wq,
                                               const float* __restrict__ bq,
                                               float* __restrict__ q) {
    int wave = (blockIdx.x * 256 + threadIdx.x) >> 6;   // 2048 waves
    int lane = threadIdx.x & 63;
    int o0 = wave * 16;
    for (int j = 0; j < 16; ++j) {
        int o = o0 + j;                 // < 32768
        int b = o >> 10, i = o & 1023;
        const float4* wr = (const float4*)(Wq + (size_t)i * NC);
        const float4* mr = (const float4*)(mean + (size_t)b * NC);
        float acc = 0.f;
#pragma unroll
        for (int e = 0; e < 4; ++e) {
            float4 w4 = wr[lane * 4 + e];
            float4 m4 = mr[lane * 4 + e];
            acc += w4.x * m4.x + w4.y * m4.y + w4.z * m4.z + w4.w * m4.w;
        }
#pragma unroll
        for (int off = 32; off; off >>= 1) acc += __shfl_xor(acc, off);
        if (lane == 0) q[o] = acc + bq[i];
    }
}

// branchless top-8 insert, all-static indexing (keeps s/si in VGPRs)
#define BUBBLE8(v, vi, s, si)                                   \
    {                                                           \
        float _v = (v); int _vi = (vi);                         \
        _Pragma("unroll")                                       \
        for (int _u = 0; _u < 8; ++_u) {                        \
            bool _gt = _v > s[_u];                              \
            float _ts = _gt ? _v : s[_u];                       \
            int _ti = _gt ? _vi : si[_u];                       \
            _v = _gt ? s[_u] : _v;                              \
            _vi = _gt ? si[_u] : _vi;                           \
            s[_u] = _ts; si[_u] = _ti;                          \
        }                                                       \
    }

// Scores: block = 128 m x 32 b. 4 waves = (mhalf, bhalf); lanes mgrp16 x cgrp4.
// Thread: acc[4 m][16 b] over its c-quad slice. q lane-private from global
// (L1/L2-hot, 64B/instr), loaded in FOUR bb-quads of 4 to cap live regs (~118
// total -> fits 170-cap from launch_bounds(256,3); no spill).
// x-tile LDS double-buffered: 4 ds_read_b128 + 2 ds_write per 256 v_fma.
__global__ __launch_bounds__(256, 3) void scores_topk_k(const float* __restrict__ memb,
                                                        const float* __restrict__ q,
                                                        float* __restrict__ candS,
                                                        int* __restrict__ candI) {
    __shared__ __align__(16) float smemf[5760];   // 23 KB: tiles(4128f) | scores | tree
    float4* smem = (float4*)smemf;
    int tid = threadIdx.x, lane = tid & 63, wid = tid >> 6;
    int mhalf = wid & 1, bhalf = wid >> 1;
    int mgrp = lane & 15, cgrp = lane >> 4;
    int m0 = blockIdx.x * MBLK;

    float acc[4][16];
#pragma unroll
    for (int mr = 0; mr < 4; ++mr)
#pragma unroll
        for (int bb = 0; bb < 16; ++bb) acc[mr][bb] = 0.f;

    // staging: wave wid loads rows (lane, lane+64) at c-quad wid
    const float* sbase = memb + (size_t)(m0 + lane) * NC + wid * 4;
    const float* qbase = q + (size_t)(bhalf * 16) * NC + cgrp * 4;

    float4 rt0, rt1;
    rt0 = *(const float4*)(sbase);
    rt1 = *(const float4*)(sbase + 64 * NC);
    smem[wid * TROW + lane] = rt0;
    smem[wid * TROW + 64 + lane] = rt1;
    __syncthreads();

    for (int cc = 0; cc < 64; ++cc) {
        const float4* tbp = smem + (cc & 1) * (4 * TROW);
        if (cc < 63) {   // prefetch next chunk into regs; LDS-write after compute
            const float* s2 = sbase + (cc + 1) * 16;
            rt0 = *(const float4*)(s2);
            rt1 = *(const float4*)(s2 + 64 * NC);
        }
        float4 x[4];
#pragma unroll
        for (int mr = 0; mr < 4; ++mr)
            x[mr] = tbp[cgrp * TROW + mhalf * 64 + mgrp + 16 * mr];
#pragma unroll
        for (int h = 0; h < 4; ++h) {
            float4 qc[4];
#pragma unroll
            for (int bb = 0; bb < 4; ++bb)
                qc[bb] = *(const float4*)(qbase + (size_t)(h * 4 + bb) * NC + cc * 16);
#pragma unroll
            for (int mr = 0; mr < 4; ++mr)
#pragma unroll
                for (int bb = 0; bb < 4; ++bb)
                    acc[mr][h * 4 + bb] = fmaf(x[mr].x, qc[bb].x, fmaf(x[mr].y, qc[bb].y,
                                          fmaf(x[mr].z, qc[bb].z, fmaf(x[mr].w, qc[bb].w,
                                          acc[mr][h * 4 + bb]))));
        }
        if (cc < 63) {
            float4* tbn = smem + ((cc + 1) & 1) * (4 * TROW);
            tbn[wid * TROW + lane] = rt0;
            tbn[wid * TROW + 64 + lane] = rt1;
        }
        __syncthreads();
    }

    // reduce over 4 cgrp lanes; write scores [32 b][128 m]
    float* fb = smemf;   // 4096 floats
#pragma unroll
    for (int mr = 0; mr < 4; ++mr)
#pragma unroll
        for (int bb = 0; bb < 16; ++bb) {
            float v = acc[mr][bb];
            v += __shfl_xor(v, 16);
            v += __shfl_xor(v, 32);
            if (cgrp == (bb & 3))
                fb[(bhalf * 16 + bb) * MBLK + mhalf * 64 + mgrp + 16 * mr] = v * 0.03125f;
        }
    __syncthreads();

    // per-b top-8: 8 threads per b, each scans 16 scores (rotated -> <=2-way banks)
    {
        int b = tid >> 3, p = tid & 7;
        float s[8]; int si[8];
#pragma unroll
        for (int u = 0; u < 8; ++u) { s[u] = -INFINITY; si[u] = -1; }
#pragma unroll
        for (int j = 0; j < 16; ++j) {
            int ml = (p + j * 8 + b * 4) & 127;
            float v = fb[b * MBLK + ml];
            BUBBLE8(v, m0 + ml, s, si);
        }
        __syncthreads();   // scores consumed; reuse LDS for candidate tree (stride 9)
        float* cs = smemf;                    // [256][9] floats at [0,2304)
        int* ci = (int*)(smemf + 2304);       // [256][9] ints  at [2304,4608)
#pragma unroll
        for (int u = 0; u < 8; ++u) { cs[tid * 9 + u] = s[u]; ci[tid * 9 + u] = si[u]; }
        __syncthreads();
        float* csA = smemf + 4608;            // [64][9]
        int* ciA = (int*)(smemf + 5184);      // [64][9] -> ends 5760
        if (tid < 64) {
            float s2[8]; int si2[8];
#pragma unroll
            for (int u = 0; u < 8; ++u) { s2[u] = -INFINITY; si2[u] = -1; }
            int t0 = (tid >> 1) * 8 + (tid & 1) * 4;
            for (int tt = 0; tt < 4; ++tt)
#pragma unroll
                for (int u = 0; u < 8; ++u)
                    BUBBLE8(cs[(t0 + tt) * 9 + u], ci[(t0 + tt) * 9 + u], s2, si2);
#pragma unroll
            for (int u = 0; u < 8; ++u) { csA[tid * 9 + u] = s2[u]; ciA[tid * 9 + u] = si2[u]; }
        }
        __syncthreads();
        if (tid < 32) {
            float s3[8]; int si3[8];
#pragma unroll
            for (int u = 0; u < 8; ++u) { s3[u] = -INFINITY; si3[u] = -1; }
            for (int j = 0; j < 16; ++j)
                BUBBLE8(csA[(tid * 2 + (j >> 3)) * 9 + (j & 7)],
                        ciA[(tid * 2 + (j >> 3)) * 9 + (j & 7)], s3, si3);
#pragma unroll
            for (int u = 0; u < 8; ++u) {
                candS[((size_t)tid * SBLOCKS + blockIdx.x) * 8 + u] = s3[u];
                candI[((size_t)tid * SBLOCKS + blockIdx.x) * 8 + u] = si3[u];
            }
        }
    }
}

__global__ __launch_bounds__(256) void finalize_k(const float* __restrict__ candS,
                                                  const int* __restrict__ candI,
                                                  const float* __restrict__ memb,
                                                  float* __restrict__ out) {
    __shared__ float cs[2048 + 256 + 32 + 8];
    __shared__ int ci[2048 + 256 + 32 + 8];
    int b = blockIdx.x, tid = threadIdx.x;
    const float* S = candS + (size_t)b * (SBLOCKS * 8);
    const int* I = candI + (size_t)b * (SBLOCKS * 8);
    float s[8]; int si[8];
#pragma unroll
    for (int u = 0; u < 8; ++u) { s[u] = -INFINITY; si[u] = -1; }
    for (int j = 0; j < 32; ++j)
        BUBBLE8(S[tid * 32 + j], I[tid * 32 + j], s, si);
#pragma unroll
    for (int u = 0; u < 8; ++u) { cs[tid * 8 + u] = s[u]; ci[tid * 8 + u] = si[u]; }
    __syncthreads();
    if (tid < 32) {
        float s2[8]; int si2[8];
#pragma unroll
        for (int u = 0; u < 8; ++u) { s2[u] = -INFINITY; si2[u] = -1; }
        for (int j = 0; j < 64; ++j)
            BUBBLE8(cs[tid * 64 + j], ci[tid * 64 + j], s2, si2);
#pragma unroll
        for (int u = 0; u < 8; ++u) { cs[2048 + tid * 8 + u] = s2[u]; ci[2048 + tid * 8 + u] = si2[u]; }
    }
    __syncthreads();
    if (tid < 4) {
        float s3[8]; int si3[8];
#pragma unroll
        for (int u = 0; u < 8; ++u) { s3[u] = -INFINITY; si3[u] = -1; }
        for (int j = 0; j < 64; ++j)
            BUBBLE8(cs[2048 + tid * 64 + j], ci[2048 + tid * 64 + j], s3, si3);
#pragma unroll
        for (int u = 0; u < 8; ++u) { cs[2304 + tid * 8 + u] = s3[u]; ci[2304 + tid * 8 + u] = si3[u]; }
    }
    __syncthreads();
    if (tid == 0) {
        float s4[8]; int si4[8];
#pragma unroll
        for (int u = 0; u < 8; ++u) { s4[u] = -INFINITY; si4[u] = -1; }
        for (int j = 0; j < 32; ++j)
            BUBBLE8(cs[2304 + j], ci[2304 + j], s4, si4);
        // softmax over sorted-desc top-8 (s4[0] is max)
        float m = s4[0], sum = 0.f;
        float w[8];
#pragma unroll
        for (int u = 0; u < 8; ++u) { w[u] = __expf(s4[u] - m); sum += w[u]; }
        float inv = 1.0f / sum;
#pragma unroll
        for (int u = 0; u < 8; ++u) { cs[2336 + u] = w[u] * inv; ci[2336 + u] = si4[u]; }
    }
    __syncthreads();
    float wv[8]; int ix[8];
#pragma unroll
    for (int u = 0; u < 8; ++u) { wv[u] = cs[2336 + u]; ix[u] = ci[2336 + u]; }
    float4 o = make_float4(0.f, 0.f, 0.f, 0.f);
#pragma unroll
    for (int u = 0; u < 8; ++u) {
        float4 r = ((const float4*)(memb + (size_t)ix[u] * NC))[tid];
        o.x = fmaf(wv[u], r.x, o.x);
        o.y = fmaf(wv[u], r.y, o.y);
        o.z = fmaf(wv[u], r.z, o.z);
        o.w = fmaf(wv[u], r.w, o.w);
    }
    ((float4*)(out + (size_t)b * NC))[tid] = o;
}

extern "C" void kernel_launch(void* const* d_in, const int* in_sizes, int n_in,
                              void* d_out, int out_size, void* d_ws, size_t ws_size,
                              hipStream_t stream) {
    const float* seg  = (const float*)d_in[0];
    const float* Wq   = (const float*)d_in[1];
    const float* bq   = (const float*)d_in[2];
    const float* memb = (const float*)d_in[3];
    float* ws = (float*)d_ws;
    float* part  = ws + OFF_PART;
    float* mean  = ws + OFF_MEAN;
    float* q     = ws + OFF_Q;
    float* candS = ws + OFF_CS;           // overlays part (safe: part dead by then)
    int*   candI = (int*)(ws + OFF_CI);
    float* out = (float*)d_out;

    mean_partial_k<<<NB * TCH, 256, 0, stream>>>(seg, part);
    mean_finalize_k<<<(NB * NC) / 256, 256, 0, stream>>>(part, mean);
    qproj_k<<<512, 256, 0, stream>>>(mean, Wq, bq, q);
    scores_topk_k<<<SBLOCKS, 256, 0, stream>>>(memb, q, candS, candI);
    finalize_k<<<NB, 256, 0, stream>>>(candS, candI, memb, out);
}